// Round 3
// baseline (3303.309 us; speedup 1.0000x reference)
//
#include <hip/hip_runtime.h>
#include <hip/hip_bf16.h>

typedef __hip_bfloat16 bf16;

#define N_USER 200000
#define N_ITEM 100000
#define NEDGE  1000000
#define HID    64

// ---------------------------------------------------------------------------
// Dtype-agnostic load/store: the harness may hand us fp32 (reference dtype)
// or a bf16-converted variant. A device-side detector sets isf32 once per
// launch; all float-tensor accesses go through these (uniform scalar branch).
// Per-conv slices are passed as ELEMENT offsets (dtype-independent).
// ---------------------------------------------------------------------------
__device__ __forceinline__ float ldf(const void* p, long i, int isf32) {
    if (isf32) return ((const float*)p)[i];
    return (float)((const bf16*)p)[i];
}
__device__ __forceinline__ void stf(void* p, long i, int isf32, float v) {
    if (isf32) ((float*)p)[i] = v;
    else       ((bf16*)p)[i] = (bf16)v;
}

// Detect fp32 vs bf16: read first 512 16-bit words of x as bf16. True bf16
// N(0,1) data: max |v| ~ 5.5 (biased exp <= 129). fp32 data: every other
// 16-bit word is random mantissa bits -> biased exp >= 137 (|v|>=1024 or
// inf/nan) with p~0.46 per word; over 256 words detection is certain.
__global__ void detect_kernel(const void* __restrict__ x, int* __restrict__ flag) {
    if (threadIdx.x == 0 && blockIdx.x == 0) {
        const unsigned short* p = (const unsigned short*)x;
        int f = 0;
        for (int i = 0; i < 512; i++) {
            int ex = (p[i] >> 7) & 0xFF;
            if (ex >= 137) f = 1;
        }
        *flag = f;
    }
}

// ---------------------------------------------------------------------------
// Input projection: out[n,c] = relu(sum_k x[n,k]*W[k,c] + b[c]), fp32 out.
// Block = 256 threads = 4 rows x 64 cols. W staged in LDS as fp32.
// ---------------------------------------------------------------------------
template<int K>
__global__ __launch_bounds__(256) void proj_kernel(
    const void* __restrict__ x, const void* __restrict__ W,
    const void* __restrict__ b, float* __restrict__ out, int N,
    const int* __restrict__ flagp)
{
    __shared__ float Ws[K * 64];
    __shared__ float xs[4][K];
    int isf32 = *flagp;
    int tid = threadIdx.x;
    for (int i = tid; i < K * 64; i += 256) Ws[i] = ldf(W, i, isf32);
    int row0 = blockIdx.x * 4;
    for (int i = tid; i < 4 * K; i += 256) {
        int r = i / K, k = i - r * K;
        int rr = row0 + r;
        xs[r][k] = (rr < N) ? ldf(x, (long)rr * K + k, isf32) : 0.f;
    }
    __syncthreads();
    int r = tid >> 6, c = tid & 63;
    int row = row0 + r;
    if (row >= N) return;
    float acc = ldf(b, c, isf32);
#pragma unroll
    for (int k = 0; k < K; k++) acc = fmaf(xs[r][k], Ws[k * 64 + c], acc);
    out[(long)row * 64 + c] = fmaxf(acc, 0.f);
}

// ---------------------------------------------------------------------------
// Edge message + scatter: for edge e,
//   msg[c] = relu(h_src[sidx[e]][c] + sum_k ea[e][k]*We[k][c] + be[c])
//   atomicAdd(agg[didx[e]][c], msg[c])
// One wave (64 lanes) per edge; 4 edges per 256-thread block.
// weoff/beoff: element offsets of this conv's We/be slices.
// ---------------------------------------------------------------------------
__global__ __launch_bounds__(256) void edge_kernel(
    const float* __restrict__ h_src, const void* __restrict__ ea,
    const int* __restrict__ sidx, const int* __restrict__ didx,
    const void* __restrict__ We, long weoff,
    const void* __restrict__ be, long beoff,
    float* __restrict__ agg, int E, const int* __restrict__ flagp)
{
    __shared__ float Ws[16 * 64];
    __shared__ float bs[64];
    int isf32 = *flagp;
    int tid = threadIdx.x;
    for (int i = tid; i < 16 * 64; i += 256) Ws[i] = ldf(We, weoff + i, isf32);
    if (tid < 64) bs[tid] = ldf(be, beoff + tid, isf32);
    __syncthreads();

    int w = tid >> 6, c = tid & 63;
    int e = blockIdx.x * 4 + w;
    if (e >= E) return;
    long eb = (long)e * 16;
    int s = sidx[e], d = didx[e];
    float acc = bs[c];
#pragma unroll
    for (int k = 0; k < 16; k++) acc = fmaf(ldf(ea, eb + k, isf32), Ws[k * 64 + c], acc);
    acc += h_src[(long)s * 64 + c];
    acc = fmaxf(acc, 0.f);
    atomicAdd(&agg[(long)d * 64 + c], acc);
}

// ---------------------------------------------------------------------------
// Node MLP: v = (1+eps)*h_dst + agg; t = relu(v@W1+b1); o = relu(t@W2+b2);
// optional residual (o += h_dst). Writes fp32 to outf (may alias h_dst —
// element-wise in-place safe), or flagged-dtype output to outv at element
// offset outoff (d_out is h_u then h_i, element offsets dtype-independent).
// One wave per node, 4 nodes per block; W1/W2 fp32 in LDS (32 KB).
// No thread returns before the barriers.
// ---------------------------------------------------------------------------
__global__ __launch_bounds__(256) void node_kernel(
    const float* __restrict__ h_dst, const float* __restrict__ agg,
    const void* __restrict__ W1, const void* __restrict__ b1,
    const void* __restrict__ W2, const void* __restrict__ b2,
    long woff, long boff,
    const void* __restrict__ eps, int conv, int residual,
    float* __restrict__ outf, void* __restrict__ outv, long outoff, int N,
    const int* __restrict__ flagp)
{
    __shared__ float W1s[64 * 64];
    __shared__ float W2s[64 * 64];
    __shared__ float vs[4][64];
    __shared__ float ts[4][64];
    int isf32 = *flagp;
    int tid = threadIdx.x;
    for (int i = tid; i < 64 * 64; i += 256) {
        W1s[i] = ldf(W1, woff + i, isf32);
        W2s[i] = ldf(W2, woff + i, isf32);
    }
    int w = tid >> 6, c = tid & 63;
    int n = blockIdx.x * 4 + w;
    bool valid = (n < N);
    long base = (long)n * 64;
    float eps1 = 1.f + ldf(eps, conv, isf32);
    float hv = (valid ? h_dst[base + c] : 0.f);
    float av = (valid ? agg[base + c] : 0.f);
    vs[w][c] = eps1 * hv + av;
    __syncthreads();   // covers W1s/W2s staging and vs handoff

    float t = ldf(b1, boff + c, isf32);
#pragma unroll
    for (int k = 0; k < 64; k++) t = fmaf(vs[w][k], W1s[k * 64 + c], t);
    t = fmaxf(t, 0.f);
    ts[w][c] = t;
    __syncthreads();   // ts handoff

    float o = ldf(b2, boff + c, isf32);
#pragma unroll
    for (int k = 0; k < 64; k++) o = fmaf(ts[w][k], W2s[k * 64 + c], o);
    o = fmaxf(o, 0.f);
    if (valid) {
        if (residual) o += hv;
        if (outv) stf(outv, outoff + base + c, isf32, o);
        else      outf[base + c] = o;
    }
}

extern "C" void kernel_launch(void* const* d_in, const int* in_sizes, int n_in,
                              void* d_out, int out_size, void* d_ws, size_t ws_size,
                              hipStream_t stream)
{
    const void* x_user    = d_in[0];
    const void* x_item    = d_in[1];
    const void* edge_attr = d_in[2];
    const int*  src_idx   = (const int*)d_in[3];
    const int*  dst_idx   = (const int*)d_in[4];
    const void* Wp_user   = d_in[5];
    const void* bp_user   = d_in[6];
    const void* Wp_item   = d_in[7];
    const void* bp_item   = d_in[8];
    const void* eps       = d_in[9];
    const void* We        = d_in[10];
    const void* be        = d_in[11];
    const void* W1        = d_in[12];
    const void* b1        = d_in[13];
    const void* W2        = d_in[14];
    const void* b2        = d_in[15];

    // Workspace: flag (256 floats of pad) + 38.4M floats = 153.6 MB + 1 KB.
    float* ws    = (float*)d_ws;
    int*   flag  = (int*)d_ws;
    float* h_u   = ws + 256;            // 12.8M floats
    float* h_i   = h_u + 12800000;      //  6.4M
    float* agg_u = h_i + 6400000;       // 12.8M
    float* agg_i = agg_u + 12800000;    //  6.4M

    detect_kernel<<<1, 64, 0, stream>>>(x_user, flag);

    // input projections
    proj_kernel<128><<<N_USER / 4, 256, 0, stream>>>(x_user, Wp_user, bp_user, h_u, N_USER, flag);
    proj_kernel<64><<<N_ITEM / 4, 256, 0, stream>>>(x_item, Wp_item, bp_item, h_i, N_ITEM, flag);

    // ----- layer 0: both edge convs (snapshot), then node MLPs in-place
    hipMemsetAsync(agg_i, 0, (size_t)N_ITEM * HID * sizeof(float), stream);
    hipMemsetAsync(agg_u, 0, (size_t)N_USER * HID * sizeof(float), stream);
    edge_kernel<<<NEDGE / 4, 256, 0, stream>>>(h_u, edge_attr, src_idx, dst_idx,
                                               We, 0 * 1024, be, 0 * 64, agg_i, NEDGE, flag);
    edge_kernel<<<NEDGE / 4, 256, 0, stream>>>(h_i, edge_attr, dst_idx, src_idx,
                                               We, 1 * 1024, be, 1 * 64, agg_u, NEDGE, flag);
    node_kernel<<<N_ITEM / 4, 256, 0, stream>>>(h_i, agg_i, W1, b1, W2, b2,
                                                0 * 4096, 0 * 64, eps, 0, 0,
                                                h_i, nullptr, 0, N_ITEM, flag);
    node_kernel<<<N_USER / 4, 256, 0, stream>>>(h_u, agg_u, W1, b1, W2, b2,
                                                1 * 4096, 1 * 64, eps, 1, 0,
                                                h_u, nullptr, 0, N_USER, flag);

    // ----- layer 1: residual, flagged-dtype output straight to d_out
    hipMemsetAsync(agg_i, 0, (size_t)N_ITEM * HID * sizeof(float), stream);
    hipMemsetAsync(agg_u, 0, (size_t)N_USER * HID * sizeof(float), stream);
    edge_kernel<<<NEDGE / 4, 256, 0, stream>>>(h_u, edge_attr, src_idx, dst_idx,
                                               We, 2 * 1024, be, 2 * 64, agg_i, NEDGE, flag);
    edge_kernel<<<NEDGE / 4, 256, 0, stream>>>(h_i, edge_attr, dst_idx, src_idx,
                                               We, 3 * 1024, be, 3 * 64, agg_u, NEDGE, flag);
    node_kernel<<<N_ITEM / 4, 256, 0, stream>>>(h_i, agg_i, W1, b1, W2, b2,
                                                2 * 4096, 2 * 64, eps, 2, 1,
                                                nullptr, d_out, (long)N_USER * HID, N_ITEM, flag);
    node_kernel<<<N_USER / 4, 256, 0, stream>>>(h_u, agg_u, W1, b1, W2, b2,
                                                3 * 4096, 3 * 64, eps, 3, 1,
                                                nullptr, d_out, 0, N_USER, flag);
}

// Round 4
// 2392.730 us; speedup vs baseline: 1.3806x; 1.3806x over previous
//
#include <hip/hip_runtime.h>
#include <hip/hip_bf16.h>

typedef __hip_bfloat16 bf16;

#define N_USER 200000
#define N_ITEM 100000
#define NEDGE  1000000
#define HID    64

// ---------------------------------------------------------------------------
// Dtype-agnostic access: harness data is bf16-converted (detected at runtime
// each launch — no static state, graph-safe). Offsets are ELEMENT offsets.
// ---------------------------------------------------------------------------
__device__ __forceinline__ float bf2f(unsigned int u) {
    unsigned int x = u << 16;
    float f; __builtin_memcpy(&f, &x, 4); return f;
}
__device__ __forceinline__ float ldf(const void* p, long i, int isf32) {
    if (isf32) return ((const float*)p)[i];
    return bf2f(((const unsigned short*)p)[i]);
}
__device__ __forceinline__ void stf(void* p, long i, int isf32, float v) {
    if (isf32) ((float*)p)[i] = v;
    else       ((bf16*)p)[i] = (bf16)v;
}
// Load one edge_attr row (16 elems) vectorized: fp32 = 4x float4, bf16 = 2x int4.
__device__ __forceinline__ void load_row16(const void* ea, long e, int isf32, float* v) {
    if (isf32) {
        const float4* p = (const float4*)((const float*)ea + e * 16);
        float4 a = p[0], b = p[1], c = p[2], d = p[3];
        v[0]=a.x; v[1]=a.y; v[2]=a.z; v[3]=a.w;
        v[4]=b.x; v[5]=b.y; v[6]=b.z; v[7]=b.w;
        v[8]=c.x; v[9]=c.y; v[10]=c.z; v[11]=c.w;
        v[12]=d.x; v[13]=d.y; v[14]=d.z; v[15]=d.w;
    } else {
        const int4* q = (const int4*)((const unsigned short*)ea + e * 16);
        int4 s0 = q[0], s1 = q[1];
        unsigned int w;
        w=(unsigned)s0.x; v[0]=bf2f(w & 0xffff); v[1]=bf2f(w >> 16);
        w=(unsigned)s0.y; v[2]=bf2f(w & 0xffff); v[3]=bf2f(w >> 16);
        w=(unsigned)s0.z; v[4]=bf2f(w & 0xffff); v[5]=bf2f(w >> 16);
        w=(unsigned)s0.w; v[6]=bf2f(w & 0xffff); v[7]=bf2f(w >> 16);
        w=(unsigned)s1.x; v[8]=bf2f(w & 0xffff); v[9]=bf2f(w >> 16);
        w=(unsigned)s1.y; v[10]=bf2f(w & 0xffff); v[11]=bf2f(w >> 16);
        w=(unsigned)s1.z; v[12]=bf2f(w & 0xffff); v[13]=bf2f(w >> 16);
        w=(unsigned)s1.w; v[14]=bf2f(w & 0xffff); v[15]=bf2f(w >> 16);
    }
}

// fp32-vs-bf16 detector (R3-verified): fp32's interleaved mantissa halves hit
// biased exp >= 137 with p~0.46/word; true bf16 N(0,1) never does.
__global__ void detect_kernel(const void* __restrict__ x, int* __restrict__ flag) {
    if (threadIdx.x == 0 && blockIdx.x == 0) {
        const unsigned short* p = (const unsigned short*)x;
        int f = 0;
        for (int i = 0; i < 512; i++) {
            int ex = (p[i] >> 7) & 0xFF;
            if (ex >= 137) f = 1;
        }
        *flag = f;
    }
}

// ---------------------------------------------------------------------------
// CSR build: histogram -> single-workgroup chunked exclusive scan -> scatter.
// cursor doubles as the degree array (read-before-overwrite is per-thread).
// ---------------------------------------------------------------------------
__global__ __launch_bounds__(256) void hist_kernel(
    const int* __restrict__ key, int* __restrict__ cnt, int E)
{
    int e = blockIdx.x * 256 + threadIdx.x;
    if (e < E) atomicAdd(&cnt[key[e]], 1);
}

__global__ __launch_bounds__(1024) void scan_kernel(
    const int* __restrict__ deg, int* __restrict__ rowptr,
    int* __restrict__ cursor, int N)
{
    __shared__ int ssum[1024];
    __shared__ int s_carry;
    int tid = threadIdx.x;
    if (tid == 0) s_carry = 0;
    __syncthreads();
    for (int base = 0; base < N; base += 8192) {
        int i0 = base + tid * 8;
        int v[8]; int tot = 0;
#pragma unroll
        for (int k = 0; k < 8; k++) { int i = i0 + k; v[k] = (i < N) ? deg[i] : 0; tot += v[k]; }
        ssum[tid] = tot;
        __syncthreads();
        for (int off = 1; off < 1024; off <<= 1) {
            int t = (tid >= off) ? ssum[tid - off] : 0;
            __syncthreads();
            ssum[tid] += t;
            __syncthreads();
        }
        int exc = ssum[tid] - tot + s_carry;
#pragma unroll
        for (int k = 0; k < 8; k++) {
            int i = i0 + k;
            if (i < N) { rowptr[i] = exc; cursor[i] = exc; }
            exc += v[k];
        }
        __syncthreads();
        if (tid == 1023) s_carry += ssum[1023];
        __syncthreads();
    }
    if (tid == 0) rowptr[N] = s_carry;
}

__global__ __launch_bounds__(256) void scatter_kernel(
    const int* __restrict__ key, const int* __restrict__ other,
    int* __restrict__ cursor, int2* __restrict__ perm, int E)
{
    int e = blockIdx.x * 256 + threadIdx.x;
    if (e >= E) return;
    int p = atomicAdd(&cursor[key[e]], 1);
    perm[p] = make_int2(e, other[e]);
}

// ---------------------------------------------------------------------------
// Input projection (grid-stride): out[n,c] = relu(x[n,:]@W[:,c] + b[c]).
// Block = 4 rows x 64 cols; W fp32 in LDS staged once per block.
// ---------------------------------------------------------------------------
template<int K>
__global__ __launch_bounds__(256) void proj_kernel(
    const void* __restrict__ x, const void* __restrict__ W,
    const void* __restrict__ b, float* __restrict__ out, int N,
    const int* __restrict__ flagp)
{
    __shared__ float Ws[K * 64];
    __shared__ float xs[4][K];
    int isf32 = *flagp;
    int tid = threadIdx.x;
    for (int i = tid; i < K * 64; i += 256) Ws[i] = ldf(W, i, isf32);
    int r = tid >> 6, c = tid & 63;
    float bc = ldf(b, c, isf32);
    for (int row0 = blockIdx.x * 4; row0 < N; row0 += gridDim.x * 4) {
        __syncthreads();   // WAR on xs (and Ws staging, first iter)
        for (int i = tid; i < 4 * K; i += 256) {
            int rr = i / K, k = i - rr * K;
            int row = row0 + rr;
            xs[rr][k] = (row < N) ? ldf(x, (long)row * K + k, isf32) : 0.f;
        }
        __syncthreads();
        int row = row0 + r;
        float acc = bc;
#pragma unroll
        for (int k = 0; k < K; k++) acc = fmaf(xs[r][k], Ws[k * 64 + c], acc);
        if (row < N) out[(long)row * 64 + c] = fmaxf(acc, 0.f);
    }
}

// ---------------------------------------------------------------------------
// Fused GINE conv: per dst node n (one wave each, 4 nodes/block, grid-stride):
//   acc[c]  = sum_{j in CSR[n]} relu(h_src[src_j][c] + ea[e_j]@We[:,c] + be[c])
//   v       = (1+eps)*h_dst[n] + acc
//   o       = relu( relu(v@W1+b1) @ W2 + b2 )   (+ h_dst[n] if RESID)
// No atomics. Weights staged once per block (39 KB LDS -> 4 blocks/CU).
// 4-edge unrolled chunks give ~12 outstanding gathers per wave.
// ---------------------------------------------------------------------------
template<int RESID>
__global__ __launch_bounds__(256, 4) void conv_kernel(
    const float* __restrict__ h_src, const float* __restrict__ h_dst,
    const int* __restrict__ rowptr, const int2* __restrict__ perm,
    const void* __restrict__ ea,
    const void* __restrict__ We, long weoff, const void* __restrict__ be, long beoff,
    const void* __restrict__ W1, const void* __restrict__ b1,
    const void* __restrict__ W2, const void* __restrict__ b2, long woff, long boff,
    const void* __restrict__ eps, int conv,
    float* __restrict__ outf, void* __restrict__ outv, long outoff,
    int N, const int* __restrict__ flagp)
{
    __shared__ float Wes[16 * 64];
    __shared__ float W1s[64 * 64];
    __shared__ float W2s[64 * 64];
    __shared__ float bes[64], b1s[64], b2s[64];
    __shared__ float vs[4][64], ts[4][64];
    int isf32 = *flagp;
    int tid = threadIdx.x;
    for (int i = tid; i < 4096; i += 256) {
        W1s[i] = ldf(W1, woff + i, isf32);
        W2s[i] = ldf(W2, woff + i, isf32);
    }
    for (int i = tid; i < 1024; i += 256) Wes[i] = ldf(We, weoff + i, isf32);
    if (tid < 64) {
        bes[tid] = ldf(be, beoff + tid, isf32);
        b1s[tid] = ldf(b1, boff + tid, isf32);
        b2s[tid] = ldf(b2, boff + tid, isf32);
    }
    __syncthreads();
    float eps1 = 1.f + ldf(eps, conv, isf32);
    int w = tid >> 6, c = tid & 63;

    for (int n0 = blockIdx.x * 4; n0 < N; n0 += gridDim.x * 4) {
        int n = n0 + w;
        float acc = 0.f, hv = 0.f;
        if (n < N) {
            hv = h_dst[(long)n * 64 + c];
            int jb = rowptr[n], je = rowptr[n + 1];
            int j = jb;
            for (; j + 4 <= je; j += 4) {
                int2 p0 = perm[j], p1 = perm[j+1], p2 = perm[j+2], p3 = perm[j+3];
                float a0[16], a1[16], a2[16], a3[16];
                load_row16(ea, p0.x, isf32, a0);
                load_row16(ea, p1.x, isf32, a1);
                load_row16(ea, p2.x, isf32, a2);
                load_row16(ea, p3.x, isf32, a3);
                float h0 = h_src[(long)p0.y * 64 + c];
                float h1 = h_src[(long)p1.y * 64 + c];
                float h2 = h_src[(long)p2.y * 64 + c];
                float h3 = h_src[(long)p3.y * 64 + c];
                float m0 = bes[c], m1 = m0, m2 = m0, m3 = m0;
#pragma unroll
                for (int k = 0; k < 16; k++) {
                    float wv = Wes[k * 64 + c];
                    m0 = fmaf(a0[k], wv, m0); m1 = fmaf(a1[k], wv, m1);
                    m2 = fmaf(a2[k], wv, m2); m3 = fmaf(a3[k], wv, m3);
                }
                acc += fmaxf(m0 + h0, 0.f); acc += fmaxf(m1 + h1, 0.f);
                acc += fmaxf(m2 + h2, 0.f); acc += fmaxf(m3 + h3, 0.f);
            }
            for (; j < je; j++) {
                int2 p0 = perm[j];
                float a0[16];
                load_row16(ea, p0.x, isf32, a0);
                float h0 = h_src[(long)p0.y * 64 + c];
                float m0 = bes[c];
#pragma unroll
                for (int k = 0; k < 16; k++) m0 = fmaf(a0[k], Wes[k * 64 + c], m0);
                acc += fmaxf(m0 + h0, 0.f);
            }
        }
        vs[w][c] = eps1 * hv + acc;
        __syncthreads();   // uniform trip count: loop bound depends only on blockIdx
        float t = b1s[c];
#pragma unroll
        for (int k = 0; k < 64; k++) t = fmaf(vs[w][k], W1s[k * 64 + c], t);
        t = fmaxf(t, 0.f);
        ts[w][c] = t;
        __syncthreads();
        float o = b2s[c];
#pragma unroll
        for (int k = 0; k < 64; k++) o = fmaf(ts[w][k], W2s[k * 64 + c], o);
        o = fmaxf(o, 0.f);
        if (n < N) {
            if (RESID) o += hv;
            long base = (long)n * 64;
            if (outv) stf(outv, outoff + base + c, isf32, o);
            else      outf[base + c] = o;
        }
    }
}

extern "C" void kernel_launch(void* const* d_in, const int* in_sizes, int n_in,
                              void* d_out, int out_size, void* d_ws, size_t ws_size,
                              hipStream_t stream)
{
    const void* x_user    = d_in[0];
    const void* x_item    = d_in[1];
    const void* edge_attr = d_in[2];
    const int*  src_idx   = (const int*)d_in[3];
    const int*  dst_idx   = (const int*)d_in[4];
    const void* Wp_user   = d_in[5];
    const void* bp_user   = d_in[6];
    const void* Wp_item   = d_in[7];
    const void* bp_item   = d_in[8];
    const void* eps       = d_in[9];
    const void* We        = d_in[10];
    const void* be        = d_in[11];
    const void* W1        = d_in[12];
    const void* b1        = d_in[13];
    const void* W2        = d_in[14];
    const void* b2        = d_in[15];

    // Workspace layout (4B elements, 256-aligned): 43.0M elems = 172 MB.
    float* ws   = (float*)d_ws;
    int*  flag  = (int*)d_ws;
    float* h_u  = ws + 256;             // 12.8M
    float* h_i  = h_u + 12800000;       //  6.4M
    float* h_u2 = h_i + 6400000;        // 12.8M
    float* h_i2 = h_u2 + 12800000;      //  6.4M
    int* rowptr_i = (int*)(h_i2 + 6400000);   // 100,001 (pad 100,096)
    int* cursor_i = rowptr_i + 100096;        // 100,000 (pad 100,096); also deg
    int2* perm_i  = (int2*)(cursor_i + 100096);  // 1M int2
    int* rowptr_u = (int*)(perm_i + 1000000); // 200,001 (pad 200,192)
    int* cursor_u = rowptr_u + 200192;        // 200,000 (pad 200,192)
    int2* perm_u  = (int2*)(cursor_u + 200192);  // 1M int2

    const int EG = (NEDGE + 255) / 256;

    detect_kernel<<<1, 64, 0, stream>>>(x_user, flag);

    // CSR by item (dst of fwd convs)
    hipMemsetAsync(cursor_i, 0, N_ITEM * sizeof(int), stream);
    hist_kernel<<<EG, 256, 0, stream>>>(dst_idx, cursor_i, NEDGE);
    scan_kernel<<<1, 1024, 0, stream>>>(cursor_i, rowptr_i, cursor_i, N_ITEM);
    scatter_kernel<<<EG, 256, 0, stream>>>(dst_idx, src_idx, cursor_i, perm_i, NEDGE);
    // CSR by user (dst of rev convs)
    hipMemsetAsync(cursor_u, 0, N_USER * sizeof(int), stream);
    hist_kernel<<<EG, 256, 0, stream>>>(src_idx, cursor_u, NEDGE);
    scan_kernel<<<1, 1024, 0, stream>>>(cursor_u, rowptr_u, cursor_u, N_USER);
    scatter_kernel<<<EG, 256, 0, stream>>>(src_idx, dst_idx, cursor_u, perm_u, NEDGE);

    // input projections
    proj_kernel<128><<<1024, 256, 0, stream>>>(x_user, Wp_user, bp_user, h_u, N_USER, flag);
    proj_kernel<64><<<1024, 256, 0, stream>>>(x_item, Wp_item, bp_item, h_i, N_ITEM, flag);

    // layer 0: snapshot (h_u,h_i) -> (h_u2,h_i2), fp32, no residual
    conv_kernel<0><<<1024, 256, 0, stream>>>(h_u, h_i, rowptr_i, perm_i, edge_attr,
        We, 0 * 1024, be, 0 * 64, W1, b1, W2, b2, 0 * 4096, 0 * 64,
        eps, 0, h_i2, nullptr, 0, N_ITEM, flag);
    conv_kernel<0><<<1024, 256, 0, stream>>>(h_i, h_u, rowptr_u, perm_u, edge_attr,
        We, 1 * 1024, be, 1 * 64, W1, b1, W2, b2, 1 * 4096, 1 * 64,
        eps, 1, h_u2, nullptr, 0, N_USER, flag);

    // layer 1: (h_u2,h_i2) -> d_out (flagged dtype), residual
    conv_kernel<1><<<1024, 256, 0, stream>>>(h_u2, h_i2, rowptr_i, perm_i, edge_attr,
        We, 2 * 1024, be, 2 * 64, W1, b1, W2, b2, 2 * 4096, 2 * 64,
        eps, 2, nullptr, d_out, (long)N_USER * HID, N_ITEM, flag);
    conv_kernel<1><<<1024, 256, 0, stream>>>(h_i2, h_u2, rowptr_u, perm_u, edge_attr,
        We, 3 * 1024, be, 3 * 64, W1, b1, W2, b2, 3 * 4096, 3 * 64,
        eps, 3, nullptr, d_out, 0, N_USER, flag);
}